// Round 7
// baseline (798.042 us; speedup 1.0000x reference)
//
#include <hip/hip_runtime.h>
#include <cstdint>
#include <type_traits>

typedef unsigned int u32;
typedef unsigned short u16;
typedef short v8s __attribute__((ext_vector_type(8)));
typedef float v4f __attribute__((ext_vector_type(4)));

#define B_ 8
#define C_ 192
#define HW_ 16384
#define C4_ 768

__device__ __forceinline__ float b2f(u16 u) {
  union { u32 i; float f; } v; v.i = ((u32)u) << 16; return v.f;
}
__device__ __forceinline__ u16 f2b(float f) {
  union { float f; u32 i; } v; v.f = f;
  u32 r = v.i + 0x7fffu + ((v.i >> 16) & 1u);
  return (u16)(r >> 16);
}
__device__ __forceinline__ void b2f2(u32 u, float& a, float& b) {
  union { u32 i; float f; } x, y;
  x.i = u << 16; y.i = u & 0xffff0000u;
  a = x.f; b = y.f;
}
__device__ __forceinline__ float sigm(float x) { return 1.f / (1.f + expf(-x)); }
__device__ __forceinline__ u32 pk2(u16 a, u16 b) { return (u32)a | ((u32)b << 16); }

// ---------------- weights fp32 -> bf16 (both weight tensors, one launch) ----------------
__global__ __launch_bounds__(256) void k_f2bw(const float* __restrict__ wqkv, const float* __restrict__ wproj,
                                              u16* __restrict__ wqb, u16* __restrict__ wpb) {
  int i = blockIdx.x * 256 + threadIdx.x;
  if (i < 147456) wqb[i] = f2b(wqkv[i]);
  else if (i < 147456 + 36864) { int j = i - 147456; wpb[j] = f2b(wproj[j]); }
}

// ---------------- channel avg/max pool over HW ----------------
__global__ __launch_bounds__(256) void k_channel_pool(const float* __restrict__ x,
                                                      float* __restrict__ avg, float* __restrict__ mx_) {
  int c = blockIdx.x, b = blockIdx.y, t = threadIdx.x;
  const float4* p = (const float4*)(x + (((size_t)b * C_ + c) << 14));
  float s = 0.f, m = -INFINITY;
  for (int i = t; i < 4096; i += 256) {
    float4 v = p[i];
    s += v.x + v.y + v.z + v.w;
    m = fmaxf(m, fmaxf(fmaxf(v.x, v.y), fmaxf(v.z, v.w)));
  }
  __shared__ float ss[256], sm[256];
  ss[t] = s; sm[t] = m; __syncthreads();
  for (int o = 128; o > 0; o >>= 1) {
    if (t < o) { ss[t] += ss[t + o]; sm[t] = fmaxf(sm[t], sm[t + o]); }
    __syncthreads();
  }
  if (t == 0) { avg[b * C_ + c] = ss[0] * (1.f / 16384.f); mx_[b * C_ + c] = sm[0]; }
}

// ---------------- SE channel gate ----------------
__global__ __launch_bounds__(256) void k_channel_gate(const float* __restrict__ avg, const float* __restrict__ mx_,
                                                      const float* __restrict__ wfc1, const float* __restrict__ wfc2,
                                                      float* __restrict__ cgate) {
  int b = blockIdx.x, t = threadIdx.x;
  __shared__ float pool[384], sq[48];
  if (t < 192) { pool[t] = avg[b * C_ + t]; pool[192 + t] = mx_[b * C_ + t]; }
  __syncthreads();
  if (t < 48) {
    float s = 0.f;
    for (int k = 0; k < 384; ++k) s += wfc1[t * 384 + k] * pool[k];
    sq[t] = fmaxf(s, 0.f);
  }
  __syncthreads();
  if (t < 192) {
    float s = 0.f;
    for (int j = 0; j < 48; ++j) s += wfc2[t * 48 + j] * sq[j];
    cgate[b * C_ + t] = sigm(s);
  }
}

// ---------------- spatial mean/max over channels (float4 px per thread) ----------------
__global__ __launch_bounds__(256) void k_spatial_pool(const float* __restrict__ x, float* __restrict__ sp) {
  int b = blockIdx.y;
  int p4 = blockIdx.x * 256 + threadIdx.x;     // float4 index, 4096 per image
  const float4* xb = (const float4*)(x + (((size_t)b * C_) << 14)) + p4;
  float4 s; s.x = s.y = s.z = s.w = 0.f;
  float4 m; m.x = m.y = m.z = m.w = -INFINITY;
#pragma unroll 4
  for (int c = 0; c < C_; ++c) {
    float4 v = xb[(size_t)c << 12];
    s.x += v.x; s.y += v.y; s.z += v.z; s.w += v.w;
    m.x = fmaxf(m.x, v.x); m.y = fmaxf(m.y, v.y);
    m.z = fmaxf(m.z, v.z); m.w = fmaxf(m.w, v.w);
  }
  float4 sm;
  sm.x = s.x * (1.f / 192.f); sm.y = s.y * (1.f / 192.f);
  sm.z = s.z * (1.f / 192.f); sm.w = s.w * (1.f / 192.f);
  *(float4*)(sp + (size_t)b * 32768 + p4 * 4) = sm;
  *(float4*)(sp + (size_t)b * 32768 + 16384 + p4 * 4) = m;
}

// ---------------- 7x7 conv (2->1 ch) + sigmoid ----------------
__global__ __launch_bounds__(256) void k_spatial_conv(const float* __restrict__ sp, const float* __restrict__ wsp,
                                                      float* __restrict__ sg) {
  int b = blockIdx.y;
  int p = blockIdx.x * 256 + threadIdx.x;
  int y = p >> 7, xx = p & 127;
  const float* s0 = sp + (size_t)b * 32768;
  float acc = 0.f;
  for (int ic = 0; ic < 2; ++ic)
    for (int ky = 0; ky < 7; ++ky) {
      int yy = y + ky - 3;
      if ((unsigned)yy >= 128u) continue;
      for (int kx = 0; kx < 7; ++kx) {
        int xp = xx + kx - 3;
        if ((unsigned)xp >= 128u) continue;
        acc += wsp[ic * 49 + ky * 7 + kx] * s0[ic * 16384 + yy * 128 + xp];
      }
    }
  sg[(size_t)b * 16384 + p] = sigm(acc);
}

// ---------------- gated x, transposed to [hw][c] bf16 ----------------
// Thread = (px-quad, channel-unit of 4 consecutive c): packed ds_write_b64 (12/thread vs 48 scalar).
__global__ __launch_bounds__(256) void k_gxT(const float* __restrict__ x, const float* __restrict__ cg,
                                             const float* __restrict__ sg, u16* __restrict__ gxT, int b0) {
  int zb = blockIdx.y, b = b0 + zb, t = threadIdx.x;
  int hw0 = blockIdx.x * 64;
  __shared__ alignas(16) u16 Ls[64][196];   // row stride 392 B (8-aligned)
  int pq = t & 15, cu = t >> 4;
  int px0 = pq * 4;
  float4 sg4 = *(const float4*)(sg + (size_t)b * 16384 + hw0 + px0);
  float sgp[4] = {sg4.x, sg4.y, sg4.z, sg4.w};
#pragma unroll
  for (int it = 0; it < 3; ++it) {
    int c0 = (it * 16 + cu) * 4;
    float cg0 = cg[b * C_ + c0],     cg1 = cg[b * C_ + c0 + 1];
    float cg2 = cg[b * C_ + c0 + 2], cg3 = cg[b * C_ + c0 + 3];
    float4 v0 = *(const float4*)(x + (((size_t)b * C_ + c0    ) << 14) + hw0 + px0);
    float4 v1 = *(const float4*)(x + (((size_t)b * C_ + c0 + 1) << 14) + hw0 + px0);
    float4 v2 = *(const float4*)(x + (((size_t)b * C_ + c0 + 2) << 14) + hw0 + px0);
    float4 v3 = *(const float4*)(x + (((size_t)b * C_ + c0 + 3) << 14) + hw0 + px0);
    float p0[4] = {v0.x, v0.y, v0.z, v0.w};
    float p1[4] = {v1.x, v1.y, v1.z, v1.w};
    float p2[4] = {v2.x, v2.y, v2.z, v2.w};
    float p3[4] = {v3.x, v3.y, v3.z, v3.w};
#pragma unroll
    for (int p = 0; p < 4; ++p) {
      uint2 w;
      w.x = pk2(f2b(p0[p] * cg0 * sgp[p]), f2b(p1[p] * cg1 * sgp[p]));
      w.y = pk2(f2b(p2[p] * cg2 * sgp[p]), f2b(p3[p] * cg3 * sgp[p]));
      *(uint2*)&Ls[px0 + p][c0] = w;
    }
  }
  __syncthreads();
  uint4* out4 = (uint4*)gxT;                // 24 uint4 per output row (192 u16)
#pragma unroll
  for (int r = 0; r < 6; ++r) {
    int ci = r * 256 + t;                   // 64 rows * 24 uint4
    int row = ci / 24, col4 = ci - row * 24;
    uint2 a = *(const uint2*)&Ls[row][col4 * 8];
    uint2 bq = *(const uint2*)&Ls[row][col4 * 8 + 4];
    uint4 v; v.x = a.x; v.y = a.y; v.z = bq.x; v.w = bq.y;
    out4[((size_t)zb * HW_ + hw0 + row) * 24 + col4] = v;
  }
}

// ---------------- bf16 MFMA GEMM: C[b][M][16384] = A[M][192] * BT[b][16384][192]^T ----------------
// BK=96 (2 k-iterations, 4 barriers) + per-wave LDS repack epilogue for wide stores.
template <int M, typename OutT>
__global__ __launch_bounds__(256) void gemm_bt(const u16* __restrict__ A, const u16* __restrict__ BT,
                                               OutT* __restrict__ C) {
  const int K = 192;
  int b = blockIdx.z;
  int n0 = blockIdx.x * 128, m0 = blockIdx.y * 128;
  const u16* Bb = BT + (size_t)b * HW_ * K;
  __shared__ alignas(16) u16 SMEM[2 * 128 * 104];    // 53248 B
  u16 (*As)[104] = (u16(*)[104])SMEM;
  u16 (*Bs)[104] = (u16(*)[104])(SMEM + 128 * 104);
  int t = threadIdx.x;
  int wave = t >> 6, lane = t & 63, l16 = lane & 15, quad = lane >> 4;
  int wr = wave >> 1, wc = wave & 1;
  v4f acc[4][4] = {};
  for (int kc = 0; kc < K; kc += 96) {
#pragma unroll
    for (int r = 0; r < 6; ++r) {
      int ci = r * 256 + t;          // 1536 chunks of 8 bf16 per operand
      int row = ci / 12, ks = (ci - row * 12) * 8;
      uint4 av; av.x = av.y = av.z = av.w = 0u;
      if (M >= 768 || m0 + row < M) av = *(const uint4*)(A + (size_t)(m0 + row) * K + kc + ks);
      *(uint4*)&As[row][ks] = av;
      uint4 bv = *(const uint4*)(Bb + (size_t)(n0 + row) * K + kc + ks);
      *(uint4*)&Bs[row][ks] = bv;
    }
    __syncthreads();
#pragma unroll
    for (int s = 0; s < 3; ++s) {
      v8s af[4], bf[4];
#pragma unroll
      for (int mt = 0; mt < 4; ++mt) af[mt] = *(const v8s*)&As[wr * 64 + mt * 16 + l16][s * 32 + quad * 8];
#pragma unroll
      for (int nt = 0; nt < 4; ++nt) bf[nt] = *(const v8s*)&Bs[wc * 64 + nt * 16 + l16][s * 32 + quad * 8];
#pragma unroll
      for (int mt = 0; mt < 4; ++mt)
#pragma unroll
        for (int nt = 0; nt < 4; ++nt)
          acc[mt][nt] = __builtin_amdgcn_mfma_f32_16x16x32_bf16(af[mt], bf[nt], acc[mt][nt], 0, 0, 0);
    }
    __syncthreads();
  }
  // epilogue: per-wave private LDS region (10240 B), repack to 16B stores
  char* eb = (char*)SMEM + wave * 10240;
  if constexpr (std::is_same<OutT, u16>::value) {
#pragma unroll
    for (int mt = 0; mt < 4; ++mt)
#pragma unroll
      for (int nt = 0; nt < 4; ++nt)
#pragma unroll
        for (int r = 0; r < 4; ++r) {
          int rr = mt * 16 + quad * 4 + r;
          *(u16*)(eb + rr * 160 + (nt * 16 + l16) * 2) = f2b(acc[mt][nt][r]);
        }
#pragma unroll
    for (int it = 0; it < 8; ++it) {
      int rr = it * 8 + (lane >> 3);
      uint4 v = *(const uint4*)(eb + rr * 160 + (lane & 7) * 16);
      int gm = m0 + wr * 64 + rr;      // M=768: always in-bounds
      size_t off = ((size_t)b * M + gm) * (size_t)HW_ + n0 + wc * 64 + (lane & 7) * 8;
      *(uint4*)(C + off) = v;
    }
  } else {
#pragma unroll
    for (int half = 0; half < 2; ++half) {
#pragma unroll
      for (int mt = 0; mt < 2; ++mt)
#pragma unroll
        for (int nt = 0; nt < 4; ++nt)
#pragma unroll
          for (int r = 0; r < 4; ++r) {
            int rr = mt * 16 + quad * 4 + r;
            *(float*)(eb + rr * 272 + (nt * 16 + l16) * 4) = acc[half * 2 + mt][nt][r];
          }
#pragma unroll
      for (int it = 0; it < 8; ++it) {
        int rr = it * 4 + (lane >> 4);
        uint4 v = *(const uint4*)(eb + rr * 272 + (lane & 15) * 16);
        int gm = m0 + wr * 64 + half * 32 + rr;
        if (gm < M) {
          size_t off = ((size_t)b * M + gm) * (size_t)HW_ + n0 + wc * 64 + (lane & 15) * 4;
          *(uint4*)((float*)C + off) = v;
        }
      }
    }
  }
}

// ---------------- depthwise 3x3 (bf16 in/out, fp32 acc), whole channel in LDS ----------------
// One block per (batch, channel); fused q/k inverse-L2-norm via block LDS tree reduction.
__global__ __launch_bounds__(256) void k_dw(const u16* __restrict__ in, const float* __restrict__ wdw,
                                            u16* __restrict__ out, float* __restrict__ rqn,
                                            float* __restrict__ rkn, int b0) {
  int oc = blockIdx.x, zb = blockIdx.y;
  size_t base = ((size_t)(zb * C4_ + oc)) << 14;
  int t = threadIdx.x;
  __shared__ alignas(16) u16 Ls[128][128];
  __shared__ float red[256];
  const uint4* gin = (const uint4*)(in + base);
#pragma unroll
  for (int r = 0; r < 8; ++r) {
    int ci = r * 256 + t;            // 2048 uint4 chunks; 16 chunks per 128-px row
    *(uint4*)&Ls[ci >> 4][(ci & 15) << 3] = gin[ci];
  }
  __syncthreads();
  const float* wd = wdw + oc * 9;
  float w0 = wd[0], w1 = wd[1], w2 = wd[2];
  float w3 = wd[3], w4 = wd[4], w5 = wd[5];
  float w6 = wd[6], w7 = wd[7], w8 = wd[8];
  int x0 = (t & 15) << 3;            // 8-px column segment
  int ybase = (t >> 4) << 3;         // 8 output rows per thread

  float rw[3][10];
  auto ldrow = [&](int yy, float* d) {
    if ((unsigned)yy < 128u) {
      uint4 v = *(const uint4*)&Ls[yy][x0];
      b2f2(v.x, d[1], d[2]); b2f2(v.y, d[3], d[4]);
      b2f2(v.z, d[5], d[6]); b2f2(v.w, d[7], d[8]);
      d[0] = (x0 == 0) ? 0.f : b2f(Ls[yy][x0 - 1]);
      d[9] = (x0 == 120) ? 0.f : b2f(Ls[yy][x0 + 8]);
    } else {
#pragma unroll
      for (int j = 0; j < 10; ++j) d[j] = 0.f;
    }
  };
  ldrow(ybase - 1, rw[0]);
  ldrow(ybase,     rw[1]);
  bool isq = (oc < 192), isk = (oc >= 384 && oc < 576);
  float ssq = 0.f;
#pragma unroll
  for (int oy = 0; oy < 8; ++oy) {
    ldrow(ybase + oy + 1, rw[(oy + 2) % 3]);
    const float* ra = rw[oy % 3];
    const float* rb = rw[(oy + 1) % 3];
    const float* rc = rw[(oy + 2) % 3];
    float acc[8];
#pragma unroll
    for (int j = 0; j < 8; ++j) {
      acc[j] = w0 * ra[j] + w1 * ra[j + 1] + w2 * ra[j + 2]
             + w3 * rb[j] + w4 * rb[j + 1] + w5 * rb[j + 2]
             + w6 * rc[j] + w7 * rc[j + 1] + w8 * rc[j + 2];
    }
    u16 vb[8];
#pragma unroll
    for (int j = 0; j < 8; ++j) vb[j] = f2b(acc[j]);
    uint4 o;
    o.x = pk2(vb[0], vb[1]); o.y = pk2(vb[2], vb[3]);
    o.z = pk2(vb[4], vb[5]); o.w = pk2(vb[6], vb[7]);
    *(uint4*)(out + base + (((size_t)(ybase + oy)) << 7) + x0) = o;
    if (isq || isk) {
#pragma unroll
      for (int j = 0; j < 8; ++j) { float f = b2f(vb[j]); ssq += f * f; }
    }
  }
  if (isq || isk) {
    red[t] = ssq;
    __syncthreads();
    for (int o2 = 128; o2 > 0; o2 >>= 1) {
      if (t < o2) red[t] += red[t + o2];
      __syncthreads();
    }
    if (t == 0) {
      float r = 1.f / fmaxf(sqrtf(red[0]), 1e-12f);
      int b = b0 + zb;
      if (isq) rqn[b * C_ + oc] = r; else rkn[b * C_ + (oc - 384)] = r;
    }
  }
}

// ---------------- QK^T raw partial dots via MFMA, 4 waves merged in-block ----------------
// split=64 (2 chunks/block) -> 1024 blocks/dispatch = 4 blocks/CU (LDS 37.6KB allows 4).
__global__ __launch_bounds__(256) void k_qk(const u16* __restrict__ qkv, float* __restrict__ Spart, int b0) {
  int split = blockIdx.x;
  int zb = blockIdx.y >> 2, h = blockIdx.y & 3;
  int bh = (b0 + zb) * 4 + h;
  int t = threadIdx.x, w = t >> 6, lane = t & 63, l16 = lane & 15, quad = lane >> 4;
  __shared__ union U {
    struct { alignas(16) u16 Qs[48][136]; alignas(16) u16 Ks[48][136]; } qk;
    float R[4][48][49];                  // [wave][d][c], aliased after K-loop
  } Sh;
  const u16* qb = qkv + (((size_t)zb * C4_ + h * 48) << 14);
  const u16* kb = qkv + (((size_t)zb * C4_ + 384 + h * 48) << 14);
  v4f acc[3][3] = {};
  for (int chunk = 0; chunk < 2; ++chunk) {
    int nb = split * 256 + chunk * 128;
#pragma unroll
    for (int r = 0; r < 3; ++r) {
      int ci = r * 256 + t;         // 768 chunks of 8
      int row = ci >> 4, cs = (ci & 15) * 8;
      *(uint4*)&Sh.qk.Qs[row][cs] = *(const uint4*)(qb + ((size_t)row << 14) + nb + cs);
      *(uint4*)&Sh.qk.Ks[row][cs] = *(const uint4*)(kb + ((size_t)row << 14) + nb + cs);
    }
    __syncthreads();
    v8s qf[3], kf[3];
#pragma unroll
    for (int mt = 0; mt < 3; ++mt) qf[mt] = *(const v8s*)&Sh.qk.Qs[mt * 16 + l16][w * 32 + quad * 8];
#pragma unroll
    for (int nt = 0; nt < 3; ++nt) kf[nt] = *(const v8s*)&Sh.qk.Ks[nt * 16 + l16][w * 32 + quad * 8];
#pragma unroll
    for (int mt = 0; mt < 3; ++mt)
#pragma unroll
      for (int nt = 0; nt < 3; ++nt)
        acc[mt][nt] = __builtin_amdgcn_mfma_f32_16x16x32_bf16(qf[mt], kf[nt], acc[mt][nt], 0, 0, 0);
    __syncthreads();
  }
  // dump wave partials (Qs/Ks dead now) and reduce 4 -> 1 in-block
#pragma unroll
  for (int mt = 0; mt < 3; ++mt)
#pragma unroll
    for (int nt = 0; nt < 3; ++nt)
#pragma unroll
      for (int r = 0; r < 4; ++r)
        Sh.R[w][nt * 16 + l16][mt * 16 + quad * 4 + r] = acc[mt][nt][r];
  __syncthreads();
  float* out = Spart + ((size_t)split * 32 + bh) * 2304;
#pragma unroll
  for (int rr = 0; rr < 9; ++rr) {
    int e = rr * 256 + t;
    int c = e / 48, d = e - c * 48;
    out[e] = (Sh.R[0][d][c] + Sh.R[1][d][c]) + (Sh.R[2][d][c] + Sh.R[3][d][c]);
  }
}

// ---------------- fold norms+temperature, softmax rows ----------------
__global__ __launch_bounds__(256) void k_softmax(const float* __restrict__ Spart, const float* __restrict__ rqn,
                                                 const float* __restrict__ rkn, const float* __restrict__ temp,
                                                 float* __restrict__ attn, int b0) {
  int bh = b0 * 4 + blockIdx.x;
  int b = bh >> 2, h = bh & 3, t = threadIdx.x;
  __shared__ float Sm[2304];
  float tv = temp[h];
  for (int r = 0; r < 9; ++r) {
    int e = r * 256 + t;
    float s = 0.f;
#pragma unroll
    for (int p = 0; p < 64; ++p) s += Spart[((size_t)p * 32 + bh) * 2304 + e];
    int c = e / 48, d = e - c * 48;
    Sm[e] = s * rqn[b * C_ + h * 48 + c] * rkn[b * C_ + h * 48 + d] * tv;
  }
  __syncthreads();
  if (t < 48) {
    float m = -INFINITY;
#pragma unroll
    for (int d = 0; d < 48; ++d) m = fmaxf(m, Sm[t * 48 + d]);
    float ex[48];
    float sum = 0.f;
#pragma unroll
    for (int d = 0; d < 48; ++d) { ex[d] = expf(Sm[t * 48 + d] - m); sum += ex[d]; }
    float inv = 1.f / sum;
#pragma unroll
    for (int d = 0; d < 48; ++d) attn[(size_t)bh * 2304 + t * 48 + d] = ex[d] * inv;
  }
}

// ---------------- out = (attn @ v) * sigmoid(gate), stored as ogT[hw][c] bf16 ----------------
// 256-px n-tiles: LDS 34.6KB + 1024 blocks -> 4 blocks/CU (was 2).
__global__ __launch_bounds__(256) void k_av(const u16* __restrict__ qkv, const float* __restrict__ attn,
                                            u16* __restrict__ ogT, int b0) {
  int zb = blockIdx.y >> 2, h = blockIdx.y & 3;
  int bh = (b0 + zb) * 4 + h;
  int t = threadIdx.x;
  int n0 = blockIdx.x * 256;
  __shared__ alignas(16) u16 Vs[48][264];
  __shared__ alignas(16) float SlT[48][48];   // [d][c]
  for (int r = 0; r < 9; ++r) {
    int e = r * 256 + t;
    int c = e / 48, d = e - c * 48;
    SlT[d][c] = attn[(size_t)bh * 2304 + e];
  }
  const u16* vb = qkv + (((size_t)zb * C4_ + 576 + h * 48) << 14);
#pragma unroll
  for (int r = 0; r < 6; ++r) {
    int ci = r * 256 + t;           // 48 rows * 32 chunks
    int row = ci >> 5, cs = (ci & 31) * 8;
    *(uint4*)&Vs[row][cs] = *(const uint4*)(vb + ((size_t)row << 14) + n0 + cs);
  }
  __syncthreads();
  int grp = t >> 6, nl = t & 63;
  int n = n0 + nl * 4;
  float acc[12][4] = {};
  for (int d = 0; d < 48; ++d) {
    uint2 vv = *(const uint2*)&Vs[d][nl * 4];
    float v[4];
    b2f2(vv.x, v[0], v[1]); b2f2(vv.y, v[2], v[3]);
    const float4* sr = (const float4*)&SlT[d][grp * 12];
    float4 sa = sr[0], sb = sr[1], sc = sr[2];
    float sv[12] = {sa.x, sa.y, sa.z, sa.w, sb.x, sb.y, sb.z, sb.w, sc.x, sc.y, sc.z, sc.w};
#pragma unroll
    for (int cc = 0; cc < 12; ++cc)
#pragma unroll
      for (int j = 0; j < 4; ++j) acc[cc][j] += sv[cc] * v[j];
  }
  const u16* gb = qkv + (((size_t)zb * C4_ + 192 + h * 48) << 14);
#pragma unroll
  for (int cc = 0; cc < 12; ++cc) {
    int c = grp * 12 + cc;
    uint2 g4 = *(const uint2*)(gb + ((size_t)c << 14) + n);
    float g[4];
    b2f2(g4.x, g[0], g[1]); b2f2(g4.y, g[2], g[3]);
#pragma unroll
    for (int j = 0; j < 4; ++j) acc[cc][j] *= sigm(g[j]);
  }
#pragma unroll
  for (int j = 0; j < 4; ++j) {
    u16 vals[12];
#pragma unroll
    for (int cc = 0; cc < 12; ++cc) vals[cc] = f2b(acc[cc][j]);
    u16* dst = ogT + ((size_t)zb * HW_ + n + j) * 192 + h * 48 + grp * 12;
    uint2* d2 = (uint2*)dst;        // 8-byte aligned
    uint2 w0, w1, w2;
    w0.x = pk2(vals[0], vals[1]);  w0.y = pk2(vals[2], vals[3]);
    w1.x = pk2(vals[4], vals[5]);  w1.y = pk2(vals[6], vals[7]);
    w2.x = pk2(vals[8], vals[9]);  w2.y = pk2(vals[10], vals[11]);
    d2[0] = w0; d2[1] = w1; d2[2] = w2;
  }
}

// ---------------- host ----------------
extern "C" void kernel_launch(void* const* d_in, const int* in_sizes, int n_in,
                              void* d_out, int out_size, void* d_ws, size_t ws_size,
                              hipStream_t stream) {
  const float* x     = (const float*)d_in[0];
  const float* wfc1  = (const float*)d_in[1];
  const float* wfc2  = (const float*)d_in[2];
  const float* wsp   = (const float*)d_in[3];
  const float* wqkv  = (const float*)d_in[4];
  const float* wdw   = (const float*)d_in[5];
  const float* wproj = (const float*)d_in[6];
  const float* temp  = (const float*)d_in[7];
  float* out = (float*)d_out;
  char* W = (char*)d_ws;

  constexpr size_t OFF_AVG   = 0;
  constexpr size_t OFF_MAX   = 8192;
  constexpr size_t OFF_CG    = 16384;
  constexpr size_t OFF_RQN   = 24576;
  constexpr size_t OFF_RKN   = 32768;
  constexpr size_t OFF_WQB   = 40960;
  constexpr size_t OFF_WPB   = OFF_WQB + 294912;
  constexpr size_t OFF_SP    = OFF_WPB + 73728;
  constexpr size_t OFF_SG    = OFF_SP + 1048576;
  constexpr size_t OFF_ATT   = OFF_SG + 524288;
  constexpr size_t OFF_SPART = OFF_ATT + 294912;
  constexpr size_t OFF_BIG   = OFF_SPART + 18874368;  // Spart: 64 partials x 32 bh x 2304 x 4B
  const size_t GXT_B = (size_t)HW_ * 192 * 2;        // 6291456
  const size_t QKV_B = (size_t)C4_ * HW_ * 2;        // 25165824

  float* avg   = (float*)(W + OFF_AVG);
  float* mx    = (float*)(W + OFF_MAX);
  float* cg    = (float*)(W + OFF_CG);
  float* rqn   = (float*)(W + OFF_RQN);
  float* rkn   = (float*)(W + OFF_RKN);
  u16*   wqb   = (u16*)(W + OFF_WQB);
  u16*   wpb   = (u16*)(W + OFF_WPB);
  float* sp    = (float*)(W + OFF_SP);
  float* sg    = (float*)(W + OFF_SG);
  float* attn  = (float*)(W + OFF_ATT);
  float* Spart = (float*)(W + OFF_SPART);

  int NB = 8;
  while (NB > 1 && (OFF_BIG + (size_t)NB * (GXT_B + 2 * QKV_B)) > ws_size) NB >>= 1;

  u16* gxT  = (u16*)(W + OFF_BIG);
  u16* qkvr = (u16*)(W + OFF_BIG + (size_t)NB * GXT_B);
  u16* qkvd = (u16*)(W + OFF_BIG + (size_t)NB * (GXT_B + QKV_B));
  u16* ogT  = qkvr;   // qkv_raw dead once depthwise is done for the whole group

  k_f2bw<<<(184320 + 255) / 256, 256, 0, stream>>>(wqkv, wproj, wqb, wpb);
  k_channel_pool<<<dim3(C_, B_), 256, 0, stream>>>(x, avg, mx);
  k_channel_gate<<<B_, 256, 0, stream>>>(avg, mx, wfc1, wfc2, cg);
  k_spatial_pool<<<dim3(16, B_), 256, 0, stream>>>(x, sp);
  k_spatial_conv<<<dim3(64, B_), 256, 0, stream>>>(sp, wsp, sg);

  for (int b0 = 0; b0 < B_; b0 += NB) {
    k_gxT<<<dim3(256, NB), 256, 0, stream>>>(x, cg, sg, gxT, b0);
    gemm_bt<768, u16><<<dim3(128, 6, NB), 256, 0, stream>>>(wqb, gxT, qkvr);
    k_dw<<<dim3(C4_, NB), 256, 0, stream>>>(qkvr, wdw, qkvd, rqn, rkn, b0);
    k_qk<<<dim3(64, NB * 4), 256, 0, stream>>>(qkvd, Spart, b0);
    k_softmax<<<NB * 4, 256, 0, stream>>>(Spart, rqn, rkn, temp, attn, b0);
    k_av<<<dim3(64, NB * 4), 256, 0, stream>>>(qkvd, attn, ogT, b0);
    gemm_bt<192, float><<<dim3(128, 2, NB), 256, 0, stream>>>(wpb, ogT, out + (size_t)b0 * C_ * HW_);
  }
}

// Round 8
// 559.652 us; speedup vs baseline: 1.4260x; 1.4260x over previous
//
#include <hip/hip_runtime.h>
#include <cstdint>
#include <type_traits>

typedef unsigned int u32;
typedef unsigned short u16;
typedef short v8s __attribute__((ext_vector_type(8)));
typedef float v4f __attribute__((ext_vector_type(4)));

#define B_ 8
#define C_ 192
#define HW_ 16384
#define C4_ 768

__device__ __forceinline__ float b2f(u16 u) {
  union { u32 i; float f; } v; v.i = ((u32)u) << 16; return v.f;
}
__device__ __forceinline__ u16 f2b(float f) {
  union { float f; u32 i; } v; v.f = f;
  u32 r = v.i + 0x7fffu + ((v.i >> 16) & 1u);
  return (u16)(r >> 16);
}
__device__ __forceinline__ void b2f2(u32 u, float& a, float& b) {
  union { u32 i; float f; } x, y;
  x.i = u << 16; y.i = u & 0xffff0000u;
  a = x.f; b = y.f;
}
__device__ __forceinline__ float sigm(float x) { return 1.f / (1.f + expf(-x)); }
__device__ __forceinline__ u32 pk2(u16 a, u16 b) { return (u32)a | ((u32)b << 16); }

// ---------------- weights fp32 -> bf16 (both weight tensors, one launch) ----------------
__global__ __launch_bounds__(256) void k_f2bw(const float* __restrict__ wqkv, const float* __restrict__ wproj,
                                              u16* __restrict__ wqb, u16* __restrict__ wpb) {
  int i = blockIdx.x * 256 + threadIdx.x;
  if (i < 147456) wqb[i] = f2b(wqkv[i]);
  else if (i < 147456 + 36864) { int j = i - 147456; wpb[j] = f2b(wproj[j]); }
}

// ---------------- channel avg/max pool over HW ----------------
__global__ __launch_bounds__(256) void k_channel_pool(const float* __restrict__ x,
                                                      float* __restrict__ avg, float* __restrict__ mx_) {
  int c = blockIdx.x, b = blockIdx.y, t = threadIdx.x;
  const float4* p = (const float4*)(x + (((size_t)b * C_ + c) << 14));
  float s = 0.f, m = -INFINITY;
  for (int i = t; i < 4096; i += 256) {
    float4 v = p[i];
    s += v.x + v.y + v.z + v.w;
    m = fmaxf(m, fmaxf(fmaxf(v.x, v.y), fmaxf(v.z, v.w)));
  }
  __shared__ float ss[256], sm[256];
  ss[t] = s; sm[t] = m; __syncthreads();
  for (int o = 128; o > 0; o >>= 1) {
    if (t < o) { ss[t] += ss[t + o]; sm[t] = fmaxf(sm[t], sm[t + o]); }
    __syncthreads();
  }
  if (t == 0) { avg[b * C_ + c] = ss[0] * (1.f / 16384.f); mx_[b * C_ + c] = sm[0]; }
}

// ---------------- SE channel gate ----------------
__global__ __launch_bounds__(256) void k_channel_gate(const float* __restrict__ avg, const float* __restrict__ mx_,
                                                      const float* __restrict__ wfc1, const float* __restrict__ wfc2,
                                                      float* __restrict__ cgate) {
  int b = blockIdx.x, t = threadIdx.x;
  __shared__ float pool[384], sq[48];
  if (t < 192) { pool[t] = avg[b * C_ + t]; pool[192 + t] = mx_[b * C_ + t]; }
  __syncthreads();
  if (t < 48) {
    float s = 0.f;
    for (int k = 0; k < 384; ++k) s += wfc1[t * 384 + k] * pool[k];
    sq[t] = fmaxf(s, 0.f);
  }
  __syncthreads();
  if (t < 192) {
    float s = 0.f;
    for (int j = 0; j < 48; ++j) s += wfc2[t * 48 + j] * sq[j];
    cgate[b * C_ + t] = sigm(s);
  }
}

// ---------------- spatial mean/max over channels (float4 px per thread) ----------------
__global__ __launch_bounds__(256) void k_spatial_pool(const float* __restrict__ x, float* __restrict__ sp) {
  int b = blockIdx.y;
  int p4 = blockIdx.x * 256 + threadIdx.x;     // float4 index, 4096 per image
  const float4* xb = (const float4*)(x + (((size_t)b * C_) << 14)) + p4;
  float4 s; s.x = s.y = s.z = s.w = 0.f;
  float4 m; m.x = m.y = m.z = m.w = -INFINITY;
#pragma unroll 4
  for (int c = 0; c < C_; ++c) {
    float4 v = xb[(size_t)c << 12];
    s.x += v.x; s.y += v.y; s.z += v.z; s.w += v.w;
    m.x = fmaxf(m.x, v.x); m.y = fmaxf(m.y, v.y);
    m.z = fmaxf(m.z, v.z); m.w = fmaxf(m.w, v.w);
  }
  float4 sm;
  sm.x = s.x * (1.f / 192.f); sm.y = s.y * (1.f / 192.f);
  sm.z = s.z * (1.f / 192.f); sm.w = s.w * (1.f / 192.f);
  *(float4*)(sp + (size_t)b * 32768 + p4 * 4) = sm;
  *(float4*)(sp + (size_t)b * 32768 + 16384 + p4 * 4) = m;
}

// ---------------- 7x7 conv (2->1 ch) + sigmoid ----------------
__global__ __launch_bounds__(256) void k_spatial_conv(const float* __restrict__ sp, const float* __restrict__ wsp,
                                                      float* __restrict__ sg) {
  int b = blockIdx.y;
  int p = blockIdx.x * 256 + threadIdx.x;
  int y = p >> 7, xx = p & 127;
  const float* s0 = sp + (size_t)b * 32768;
  float acc = 0.f;
  for (int ic = 0; ic < 2; ++ic)
    for (int ky = 0; ky < 7; ++ky) {
      int yy = y + ky - 3;
      if ((unsigned)yy >= 128u) continue;
      for (int kx = 0; kx < 7; ++kx) {
        int xp = xx + kx - 3;
        if ((unsigned)xp >= 128u) continue;
        acc += wsp[ic * 49 + ky * 7 + kx] * s0[ic * 16384 + yy * 128 + xp];
      }
    }
  sg[(size_t)b * 16384 + p] = sigm(acc);
}

// ---------------- gated x, transposed to [hw][c] bf16 ----------------
// Thread = (px-quad, channel-unit of 4 consecutive c): packed ds_write_b64 (12/thread vs 48 scalar).
__global__ __launch_bounds__(256) void k_gxT(const float* __restrict__ x, const float* __restrict__ cg,
                                             const float* __restrict__ sg, u16* __restrict__ gxT, int b0) {
  int zb = blockIdx.y, b = b0 + zb, t = threadIdx.x;
  int hw0 = blockIdx.x * 64;
  __shared__ alignas(16) u16 Ls[64][196];   // row stride 392 B (8-aligned)
  int pq = t & 15, cu = t >> 4;
  int px0 = pq * 4;
  float4 sg4 = *(const float4*)(sg + (size_t)b * 16384 + hw0 + px0);
  float sgp[4] = {sg4.x, sg4.y, sg4.z, sg4.w};
#pragma unroll
  for (int it = 0; it < 3; ++it) {
    int c0 = (it * 16 + cu) * 4;
    float cg0 = cg[b * C_ + c0],     cg1 = cg[b * C_ + c0 + 1];
    float cg2 = cg[b * C_ + c0 + 2], cg3 = cg[b * C_ + c0 + 3];
    float4 v0 = *(const float4*)(x + (((size_t)b * C_ + c0    ) << 14) + hw0 + px0);
    float4 v1 = *(const float4*)(x + (((size_t)b * C_ + c0 + 1) << 14) + hw0 + px0);
    float4 v2 = *(const float4*)(x + (((size_t)b * C_ + c0 + 2) << 14) + hw0 + px0);
    float4 v3 = *(const float4*)(x + (((size_t)b * C_ + c0 + 3) << 14) + hw0 + px0);
    float p0[4] = {v0.x, v0.y, v0.z, v0.w};
    float p1[4] = {v1.x, v1.y, v1.z, v1.w};
    float p2[4] = {v2.x, v2.y, v2.z, v2.w};
    float p3[4] = {v3.x, v3.y, v3.z, v3.w};
#pragma unroll
    for (int p = 0; p < 4; ++p) {
      uint2 w;
      w.x = pk2(f2b(p0[p] * cg0 * sgp[p]), f2b(p1[p] * cg1 * sgp[p]));
      w.y = pk2(f2b(p2[p] * cg2 * sgp[p]), f2b(p3[p] * cg3 * sgp[p]));
      *(uint2*)&Ls[px0 + p][c0] = w;
    }
  }
  __syncthreads();
  uint4* out4 = (uint4*)gxT;                // 24 uint4 per output row (192 u16)
#pragma unroll
  for (int r = 0; r < 6; ++r) {
    int ci = r * 256 + t;                   // 64 rows * 24 uint4
    int row = ci / 24, col4 = ci - row * 24;
    uint2 a = *(const uint2*)&Ls[row][col4 * 8];
    uint2 bq = *(const uint2*)&Ls[row][col4 * 8 + 4];
    uint4 v; v.x = a.x; v.y = a.y; v.z = bq.x; v.w = bq.y;
    out4[((size_t)zb * HW_ + hw0 + row) * 24 + col4] = v;
  }
}

// ---------------- bf16 MFMA GEMM: C[b][M][16384] = A[M][192] * BT[b][16384][192]^T ----------------
// BK=96 (2 k-iterations, 4 barriers) + per-wave LDS repack epilogue for wide stores.
template <int M, typename OutT>
__global__ __launch_bounds__(256) void gemm_bt(const u16* __restrict__ A, const u16* __restrict__ BT,
                                               OutT* __restrict__ C) {
  const int K = 192;
  int b = blockIdx.z;
  int n0 = blockIdx.x * 128, m0 = blockIdx.y * 128;
  const u16* Bb = BT + (size_t)b * HW_ * K;
  __shared__ alignas(16) u16 SMEM[2 * 128 * 104];    // 53248 B
  u16 (*As)[104] = (u16(*)[104])SMEM;
  u16 (*Bs)[104] = (u16(*)[104])(SMEM + 128 * 104);
  int t = threadIdx.x;
  int wave = t >> 6, lane = t & 63, l16 = lane & 15, quad = lane >> 4;
  int wr = wave >> 1, wc = wave & 1;
  v4f acc[4][4] = {};
  for (int kc = 0; kc < K; kc += 96) {
#pragma unroll
    for (int r = 0; r < 6; ++r) {
      int ci = r * 256 + t;          // 1536 chunks of 8 bf16 per operand
      int row = ci / 12, ks = (ci - row * 12) * 8;
      uint4 av; av.x = av.y = av.z = av.w = 0u;
      if (M >= 768 || m0 + row < M) av = *(const uint4*)(A + (size_t)(m0 + row) * K + kc + ks);
      *(uint4*)&As[row][ks] = av;
      uint4 bv = *(const uint4*)(Bb + (size_t)(n0 + row) * K + kc + ks);
      *(uint4*)&Bs[row][ks] = bv;
    }
    __syncthreads();
#pragma unroll
    for (int s = 0; s < 3; ++s) {
      v8s af[4], bf[4];
#pragma unroll
      for (int mt = 0; mt < 4; ++mt) af[mt] = *(const v8s*)&As[wr * 64 + mt * 16 + l16][s * 32 + quad * 8];
#pragma unroll
      for (int nt = 0; nt < 4; ++nt) bf[nt] = *(const v8s*)&Bs[wc * 64 + nt * 16 + l16][s * 32 + quad * 8];
#pragma unroll
      for (int mt = 0; mt < 4; ++mt)
#pragma unroll
        for (int nt = 0; nt < 4; ++nt)
          acc[mt][nt] = __builtin_amdgcn_mfma_f32_16x16x32_bf16(af[mt], bf[nt], acc[mt][nt], 0, 0, 0);
    }
    __syncthreads();
  }
  // epilogue: per-wave private LDS region (10240 B), repack to 16B stores
  char* eb = (char*)SMEM + wave * 10240;
  if constexpr (std::is_same<OutT, u16>::value) {
#pragma unroll
    for (int mt = 0; mt < 4; ++mt)
#pragma unroll
      for (int nt = 0; nt < 4; ++nt)
#pragma unroll
        for (int r = 0; r < 4; ++r) {
          int rr = mt * 16 + quad * 4 + r;
          *(u16*)(eb + rr * 160 + (nt * 16 + l16) * 2) = f2b(acc[mt][nt][r]);
        }
#pragma unroll
    for (int it = 0; it < 8; ++it) {
      int rr = it * 8 + (lane >> 3);
      uint4 v = *(const uint4*)(eb + rr * 160 + (lane & 7) * 16);
      int gm = m0 + wr * 64 + rr;      // M=768: always in-bounds
      size_t off = ((size_t)b * M + gm) * (size_t)HW_ + n0 + wc * 64 + (lane & 7) * 8;
      *(uint4*)(C + off) = v;
    }
  } else {
#pragma unroll
    for (int half = 0; half < 2; ++half) {
#pragma unroll
      for (int mt = 0; mt < 2; ++mt)
#pragma unroll
        for (int nt = 0; nt < 4; ++nt)
#pragma unroll
          for (int r = 0; r < 4; ++r) {
            int rr = mt * 16 + quad * 4 + r;
            *(float*)(eb + rr * 272 + (nt * 16 + l16) * 4) = acc[half * 2 + mt][nt][r];
          }
#pragma unroll
      for (int it = 0; it < 8; ++it) {
        int rr = it * 4 + (lane >> 4);
        uint4 v = *(const uint4*)(eb + rr * 272 + (lane & 15) * 16);
        int gm = m0 + wr * 64 + half * 32 + rr;
        if (gm < M) {
          size_t off = ((size_t)b * M + gm) * (size_t)HW_ + n0 + wc * 64 + (lane & 15) * 4;
          *(uint4*)((float*)C + off) = v;
        }
      }
    }
  }
}

// ---------------- depthwise 3x3 (bf16 in/out, fp32 acc), whole channel in LDS ----------------
// One block per (batch, channel); fused q/k inverse-L2-norm via block LDS tree reduction.
__global__ __launch_bounds__(256) void k_dw(const u16* __restrict__ in, const float* __restrict__ wdw,
                                            u16* __restrict__ out, float* __restrict__ rqn,
                                            float* __restrict__ rkn, int b0) {
  int oc = blockIdx.x, zb = blockIdx.y;
  size_t base = ((size_t)(zb * C4_ + oc)) << 14;
  int t = threadIdx.x;
  __shared__ alignas(16) u16 Ls[128][128];
  __shared__ float red[256];
  const uint4* gin = (const uint4*)(in + base);
#pragma unroll
  for (int r = 0; r < 8; ++r) {
    int ci = r * 256 + t;            // 2048 uint4 chunks; 16 chunks per 128-px row
    *(uint4*)&Ls[ci >> 4][(ci & 15) << 3] = gin[ci];
  }
  __syncthreads();
  const float* wd = wdw + oc * 9;
  float w0 = wd[0], w1 = wd[1], w2 = wd[2];
  float w3 = wd[3], w4 = wd[4], w5 = wd[5];
  float w6 = wd[6], w7 = wd[7], w8 = wd[8];
  int x0 = (t & 15) << 3;            // 8-px column segment
  int ybase = (t >> 4) << 3;         // 8 output rows per thread

  float rw[3][10];
  auto ldrow = [&](int yy, float* d) {
    if ((unsigned)yy < 128u) {
      uint4 v = *(const uint4*)&Ls[yy][x0];
      b2f2(v.x, d[1], d[2]); b2f2(v.y, d[3], d[4]);
      b2f2(v.z, d[5], d[6]); b2f2(v.w, d[7], d[8]);
      d[0] = (x0 == 0) ? 0.f : b2f(Ls[yy][x0 - 1]);
      d[9] = (x0 == 120) ? 0.f : b2f(Ls[yy][x0 + 8]);
    } else {
#pragma unroll
      for (int j = 0; j < 10; ++j) d[j] = 0.f;
    }
  };
  ldrow(ybase - 1, rw[0]);
  ldrow(ybase,     rw[1]);
  bool isq = (oc < 192), isk = (oc >= 384 && oc < 576);
  float ssq = 0.f;
#pragma unroll
  for (int oy = 0; oy < 8; ++oy) {
    ldrow(ybase + oy + 1, rw[(oy + 2) % 3]);
    const float* ra = rw[oy % 3];
    const float* rb = rw[(oy + 1) % 3];
    const float* rc = rw[(oy + 2) % 3];
    float acc[8];
#pragma unroll
    for (int j = 0; j < 8; ++j) {
      acc[j] = w0 * ra[j] + w1 * ra[j + 1] + w2 * ra[j + 2]
             + w3 * rb[j] + w4 * rb[j + 1] + w5 * rb[j + 2]
             + w6 * rc[j] + w7 * rc[j + 1] + w8 * rc[j + 2];
    }
    u16 vb[8];
#pragma unroll
    for (int j = 0; j < 8; ++j) vb[j] = f2b(acc[j]);
    uint4 o;
    o.x = pk2(vb[0], vb[1]); o.y = pk2(vb[2], vb[3]);
    o.z = pk2(vb[4], vb[5]); o.w = pk2(vb[6], vb[7]);
    *(uint4*)(out + base + (((size_t)(ybase + oy)) << 7) + x0) = o;
    if (isq || isk) {
#pragma unroll
      for (int j = 0; j < 8; ++j) { float f = b2f(vb[j]); ssq += f * f; }
    }
  }
  if (isq || isk) {
    red[t] = ssq;
    __syncthreads();
    for (int o2 = 128; o2 > 0; o2 >>= 1) {
      if (t < o2) red[t] += red[t + o2];
      __syncthreads();
    }
    if (t == 0) {
      float r = 1.f / fmaxf(sqrtf(red[0]), 1e-12f);
      int b = b0 + zb;
      if (isq) rqn[b * C_ + oc] = r; else rkn[b * C_ + (oc - 384)] = r;
    }
  }
}

// ---------------- QK^T raw partial dots via MFMA, 4 waves merged in-block ----------------
// split=64 (2 chunks/block) -> 1024 blocks/dispatch = 4 blocks/CU (LDS 37.6KB allows 4).
__global__ __launch_bounds__(256) void k_qk(const u16* __restrict__ qkv, float* __restrict__ Spart, int b0) {
  int split = blockIdx.x;
  int zb = blockIdx.y >> 2, h = blockIdx.y & 3;
  int bh = (b0 + zb) * 4 + h;
  int t = threadIdx.x, w = t >> 6, lane = t & 63, l16 = lane & 15, quad = lane >> 4;
  __shared__ union U {
    struct { alignas(16) u16 Qs[48][136]; alignas(16) u16 Ks[48][136]; } qk;
    float R[4][48][49];                  // [wave][d][c], aliased after K-loop
  } Sh;
  const u16* qb = qkv + (((size_t)zb * C4_ + h * 48) << 14);
  const u16* kb = qkv + (((size_t)zb * C4_ + 384 + h * 48) << 14);
  v4f acc[3][3] = {};
  for (int chunk = 0; chunk < 2; ++chunk) {
    int nb = split * 256 + chunk * 128;
#pragma unroll
    for (int r = 0; r < 3; ++r) {
      int ci = r * 256 + t;         // 768 chunks of 8
      int row = ci >> 4, cs = (ci & 15) * 8;
      *(uint4*)&Sh.qk.Qs[row][cs] = *(const uint4*)(qb + ((size_t)row << 14) + nb + cs);
      *(uint4*)&Sh.qk.Ks[row][cs] = *(const uint4*)(kb + ((size_t)row << 14) + nb + cs);
    }
    __syncthreads();
    v8s qf[3], kf[3];
#pragma unroll
    for (int mt = 0; mt < 3; ++mt) qf[mt] = *(const v8s*)&Sh.qk.Qs[mt * 16 + l16][w * 32 + quad * 8];
#pragma unroll
    for (int nt = 0; nt < 3; ++nt) kf[nt] = *(const v8s*)&Sh.qk.Ks[nt * 16 + l16][w * 32 + quad * 8];
#pragma unroll
    for (int mt = 0; mt < 3; ++mt)
#pragma unroll
      for (int nt = 0; nt < 3; ++nt)
        acc[mt][nt] = __builtin_amdgcn_mfma_f32_16x16x32_bf16(qf[mt], kf[nt], acc[mt][nt], 0, 0, 0);
    __syncthreads();
  }
  // dump wave partials (Qs/Ks dead now) and reduce 4 -> 1 in-block
#pragma unroll
  for (int mt = 0; mt < 3; ++mt)
#pragma unroll
    for (int nt = 0; nt < 3; ++nt)
#pragma unroll
      for (int r = 0; r < 4; ++r)
        Sh.R[w][nt * 16 + l16][mt * 16 + quad * 4 + r] = acc[mt][nt][r];
  __syncthreads();
  float* out = Spart + ((size_t)split * 32 + bh) * 2304;
#pragma unroll
  for (int rr = 0; rr < 9; ++rr) {
    int e = rr * 256 + t;
    int c = e / 48, d = e - c * 48;
    out[e] = (Sh.R[0][d][c] + Sh.R[1][d][c]) + (Sh.R[2][d][c] + Sh.R[3][d][c]);
  }
}

// ---------------- parallel Spart reduction + norm/temperature fold ----------------
// grid (9, NB*4): thread owns one element, sums 64 partials with full ILP.
__global__ __launch_bounds__(256) void k_sred(const float* __restrict__ Spart, const float* __restrict__ rqn,
                                              const float* __restrict__ rkn, const float* __restrict__ temp,
                                              float* __restrict__ Sm, int b0) {
  int bh = b0 * 4 + blockIdx.y;
  int b = bh >> 2, h = bh & 3, t = threadIdx.x;
  int e = blockIdx.x * 256 + t;
  float s = 0.f;
#pragma unroll
  for (int p = 0; p < 64; ++p) s += Spart[((size_t)p * 32 + bh) * 2304 + e];
  int c = e / 48, d = e - c * 48;
  Sm[(size_t)bh * 2304 + e] = s * rqn[b * C_ + h * 48 + c] * rkn[b * C_ + h * 48 + d] * temp[h];
}

// ---------------- softmax rows (Sm pre-reduced & scaled) ----------------
__global__ __launch_bounds__(256) void k_softmax(const float* __restrict__ Sm_g, float* __restrict__ attn, int b0) {
  int bh = b0 * 4 + blockIdx.x;
  int t = threadIdx.x;
  __shared__ float Sm[2304];
  for (int r = 0; r < 9; ++r) {
    int e = r * 256 + t;
    Sm[e] = Sm_g[(size_t)bh * 2304 + e];
  }
  __syncthreads();
  if (t < 48) {
    float m = -INFINITY;
#pragma unroll
    for (int d = 0; d < 48; ++d) m = fmaxf(m, Sm[t * 48 + d]);
    float ex[48];
    float sum = 0.f;
#pragma unroll
    for (int d = 0; d < 48; ++d) { ex[d] = expf(Sm[t * 48 + d] - m); sum += ex[d]; }
    float inv = 1.f / sum;
#pragma unroll
    for (int d = 0; d < 48; ++d) attn[(size_t)bh * 2304 + t * 48 + d] = ex[d] * inv;
  }
}

// ---------------- out = (attn @ v) * sigmoid(gate), stored as ogT[hw][c] bf16 ----------------
// 256-px n-tiles: LDS 34.6KB + 1024 blocks -> 4 blocks/CU (was 2).
__global__ __launch_bounds__(256) void k_av(const u16* __restrict__ qkv, const float* __restrict__ attn,
                                            u16* __restrict__ ogT, int b0) {
  int zb = blockIdx.y >> 2, h = blockIdx.y & 3;
  int bh = (b0 + zb) * 4 + h;
  int t = threadIdx.x;
  int n0 = blockIdx.x * 256;
  __shared__ alignas(16) u16 Vs[48][264];
  __shared__ alignas(16) float SlT[48][48];   // [d][c]
  for (int r = 0; r < 9; ++r) {
    int e = r * 256 + t;
    int c = e / 48, d = e - c * 48;
    SlT[d][c] = attn[(size_t)bh * 2304 + e];
  }
  const u16* vb = qkv + (((size_t)zb * C4_ + 576 + h * 48) << 14);
#pragma unroll
  for (int r = 0; r < 6; ++r) {
    int ci = r * 256 + t;           // 48 rows * 32 chunks
    int row = ci >> 5, cs = (ci & 31) * 8;
    *(uint4*)&Vs[row][cs] = *(const uint4*)(vb + ((size_t)row << 14) + n0 + cs);
  }
  __syncthreads();
  int grp = t >> 6, nl = t & 63;
  int n = n0 + nl * 4;
  float acc[12][4] = {};
  for (int d = 0; d < 48; ++d) {
    uint2 vv = *(const uint2*)&Vs[d][nl * 4];
    float v[4];
    b2f2(vv.x, v[0], v[1]); b2f2(vv.y, v[2], v[3]);
    const float4* sr = (const float4*)&SlT[d][grp * 12];
    float4 sa = sr[0], sb = sr[1], sc = sr[2];
    float sv[12] = {sa.x, sa.y, sa.z, sa.w, sb.x, sb.y, sb.z, sb.w, sc.x, sc.y, sc.z, sc.w};
#pragma unroll
    for (int cc = 0; cc < 12; ++cc)
#pragma unroll
      for (int j = 0; j < 4; ++j) acc[cc][j] += sv[cc] * v[j];
  }
  const u16* gb = qkv + (((size_t)zb * C4_ + 192 + h * 48) << 14);
#pragma unroll
  for (int cc = 0; cc < 12; ++cc) {
    int c = grp * 12 + cc;
    uint2 g4 = *(const uint2*)(gb + ((size_t)c << 14) + n);
    float g[4];
    b2f2(g4.x, g[0], g[1]); b2f2(g4.y, g[2], g[3]);
#pragma unroll
    for (int j = 0; j < 4; ++j) acc[cc][j] *= sigm(g[j]);
  }
#pragma unroll
  for (int j = 0; j < 4; ++j) {
    u16 vals[12];
#pragma unroll
    for (int cc = 0; cc < 12; ++cc) vals[cc] = f2b(acc[cc][j]);
    u16* dst = ogT + ((size_t)zb * HW_ + n + j) * 192 + h * 48 + grp * 12;
    uint2* d2 = (uint2*)dst;        // 8-byte aligned
    uint2 w0, w1, w2;
    w0.x = pk2(vals[0], vals[1]);  w0.y = pk2(vals[2], vals[3]);
    w1.x = pk2(vals[4], vals[5]);  w1.y = pk2(vals[6], vals[7]);
    w2.x = pk2(vals[8], vals[9]);  w2.y = pk2(vals[10], vals[11]);
    d2[0] = w0; d2[1] = w1; d2[2] = w2;
  }
}

// ---------------- host ----------------
extern "C" void kernel_launch(void* const* d_in, const int* in_sizes, int n_in,
                              void* d_out, int out_size, void* d_ws, size_t ws_size,
                              hipStream_t stream) {
  const float* x     = (const float*)d_in[0];
  const float* wfc1  = (const float*)d_in[1];
  const float* wfc2  = (const float*)d_in[2];
  const float* wsp   = (const float*)d_in[3];
  const float* wqkv  = (const float*)d_in[4];
  const float* wdw   = (const float*)d_in[5];
  const float* wproj = (const float*)d_in[6];
  const float* temp  = (const float*)d_in[7];
  float* out = (float*)d_out;
  char* W = (char*)d_ws;

  constexpr size_t OFF_AVG   = 0;
  constexpr size_t OFF_MAX   = 8192;
  constexpr size_t OFF_CG    = 16384;
  constexpr size_t OFF_RQN   = 24576;
  constexpr size_t OFF_RKN   = 32768;
  constexpr size_t OFF_WQB   = 40960;
  constexpr size_t OFF_WPB   = OFF_WQB + 294912;
  constexpr size_t OFF_SP    = OFF_WPB + 73728;
  constexpr size_t OFF_SG    = OFF_SP + 1048576;
  constexpr size_t OFF_ATT   = OFF_SG + 524288;
  constexpr size_t OFF_SM    = OFF_ATT + 294912;      // scaled S: 32 bh x 2304 x 4B
  constexpr size_t OFF_SPART = OFF_SM + 294912;
  constexpr size_t OFF_BIG   = OFF_SPART + 18874368;  // Spart: 64 partials x 32 bh x 2304 x 4B
  const size_t GXT_B = (size_t)HW_ * 192 * 2;        // 6291456
  const size_t QKV_B = (size_t)C4_ * HW_ * 2;        // 25165824

  float* avg   = (float*)(W + OFF_AVG);
  float* mx    = (float*)(W + OFF_MAX);
  float* cg    = (float*)(W + OFF_CG);
  float* rqn   = (float*)(W + OFF_RQN);
  float* rkn   = (float*)(W + OFF_RKN);
  u16*   wqb   = (u16*)(W + OFF_WQB);
  u16*   wpb   = (u16*)(W + OFF_WPB);
  float* sp    = (float*)(W + OFF_SP);
  float* sg    = (float*)(W + OFF_SG);
  float* attn  = (float*)(W + OFF_ATT);
  float* Smg   = (float*)(W + OFF_SM);
  float* Spart = (float*)(W + OFF_SPART);

  int NB = 8;
  while (NB > 1 && (OFF_BIG + (size_t)NB * (GXT_B + 2 * QKV_B)) > ws_size) NB >>= 1;

  u16* gxT  = (u16*)(W + OFF_BIG);
  u16* qkvr = (u16*)(W + OFF_BIG + (size_t)NB * GXT_B);
  u16* qkvd = (u16*)(W + OFF_BIG + (size_t)NB * (GXT_B + QKV_B));
  u16* ogT  = qkvr;   // qkv_raw dead once depthwise is done for the whole group

  k_f2bw<<<(184320 + 255) / 256, 256, 0, stream>>>(wqkv, wproj, wqb, wpb);
  k_channel_pool<<<dim3(C_, B_), 256, 0, stream>>>(x, avg, mx);
  k_channel_gate<<<B_, 256, 0, stream>>>(avg, mx, wfc1, wfc2, cg);
  k_spatial_pool<<<dim3(16, B_), 256, 0, stream>>>(x, sp);
  k_spatial_conv<<<dim3(64, B_), 256, 0, stream>>>(sp, wsp, sg);

  for (int b0 = 0; b0 < B_; b0 += NB) {
    k_gxT<<<dim3(256, NB), 256, 0, stream>>>(x, cg, sg, gxT, b0);
    gemm_bt<768, u16><<<dim3(128, 6, NB), 256, 0, stream>>>(wqb, gxT, qkvr);
    k_dw<<<dim3(C4_, NB), 256, 0, stream>>>(qkvr, wdw, qkvd, rqn, rkn, b0);
    k_qk<<<dim3(64, NB * 4), 256, 0, stream>>>(qkvd, Spart, b0);
    k_sred<<<dim3(9, NB * 4), 256, 0, stream>>>(Spart, rqn, rkn, temp, Smg, b0);
    k_softmax<<<NB * 4, 256, 0, stream>>>(Smg, attn, b0);
    k_av<<<dim3(64, NB * 4), 256, 0, stream>>>(qkvd, attn, ogT, b0);
    gemm_bt<192, float><<<dim3(128, 2, NB), 256, 0, stream>>>(wpb, ogT, out + (size_t)b0 * C_ * HW_);
  }
}

// Round 9
// 492.816 us; speedup vs baseline: 1.6194x; 1.1356x over previous
//
#include <hip/hip_runtime.h>
#include <cstdint>
#include <type_traits>

typedef unsigned int u32;
typedef unsigned short u16;
typedef short v8s __attribute__((ext_vector_type(8)));
typedef float v4f __attribute__((ext_vector_type(4)));

#define B_ 8
#define C_ 192
#define HW_ 16384
#define C4_ 768

__device__ __forceinline__ float b2f(u16 u) {
  union { u32 i; float f; } v; v.i = ((u32)u) << 16; return v.f;
}
__device__ __forceinline__ u16 f2b(float f) {
  union { float f; u32 i; } v; v.f = f;
  u32 r = v.i + 0x7fffu + ((v.i >> 16) & 1u);
  return (u16)(r >> 16);
}
__device__ __forceinline__ void b2f2(u32 u, float& a, float& b) {
  union { u32 i; float f; } x, y;
  x.i = u << 16; y.i = u & 0xffff0000u;
  a = x.f; b = y.f;
}
__device__ __forceinline__ float sigm(float x) { return 1.f / (1.f + expf(-x)); }
__device__ __forceinline__ u32 pk2(u16 a, u16 b) { return (u32)a | ((u32)b << 16); }

// ---------------- weights fp32 -> bf16 (both weight tensors, one launch) ----------------
__global__ __launch_bounds__(256) void k_f2bw(const float* __restrict__ wqkv, const float* __restrict__ wproj,
                                              u16* __restrict__ wqb, u16* __restrict__ wpb) {
  int i = blockIdx.x * 256 + threadIdx.x;
  if (i < 147456) wqb[i] = f2b(wqkv[i]);
  else if (i < 147456 + 36864) { int j = i - 147456; wpb[j] = f2b(wproj[j]); }
}

// ---------------- channel avg/max pool over HW ----------------
__global__ __launch_bounds__(256) void k_channel_pool(const float* __restrict__ x,
                                                      float* __restrict__ avg, float* __restrict__ mx_) {
  int c = blockIdx.x, b = blockIdx.y, t = threadIdx.x;
  const float4* p = (const float4*)(x + (((size_t)b * C_ + c) << 14));
  float s = 0.f, m = -INFINITY;
  for (int i = t; i < 4096; i += 256) {
    float4 v = p[i];
    s += v.x + v.y + v.z + v.w;
    m = fmaxf(m, fmaxf(fmaxf(v.x, v.y), fmaxf(v.z, v.w)));
  }
  __shared__ float ss[256], sm[256];
  ss[t] = s; sm[t] = m; __syncthreads();
  for (int o = 128; o > 0; o >>= 1) {
    if (t < o) { ss[t] += ss[t + o]; sm[t] = fmaxf(sm[t], sm[t + o]); }
    __syncthreads();
  }
  if (t == 0) { avg[b * C_ + c] = ss[0] * (1.f / 16384.f); mx_[b * C_ + c] = sm[0]; }
}

// ---------------- SE channel gate ----------------
__global__ __launch_bounds__(256) void k_channel_gate(const float* __restrict__ avg, const float* __restrict__ mx_,
                                                      const float* __restrict__ wfc1, const float* __restrict__ wfc2,
                                                      float* __restrict__ cgate) {
  int b = blockIdx.x, t = threadIdx.x;
  __shared__ float pool[384], sq[48];
  if (t < 192) { pool[t] = avg[b * C_ + t]; pool[192 + t] = mx_[b * C_ + t]; }
  __syncthreads();
  if (t < 48) {
    float s = 0.f;
    for (int k = 0; k < 384; ++k) s += wfc1[t * 384 + k] * pool[k];
    sq[t] = fmaxf(s, 0.f);
  }
  __syncthreads();
  if (t < 192) {
    float s = 0.f;
    for (int j = 0; j < 48; ++j) s += wfc2[t * 48 + j] * sq[j];
    cgate[b * C_ + t] = sigm(s);
  }
}

// ---------------- spatial mean/max over channels (float4 px per thread) ----------------
__global__ __launch_bounds__(256) void k_spatial_pool(const float* __restrict__ x, float* __restrict__ sp) {
  int b = blockIdx.y;
  int p4 = blockIdx.x * 256 + threadIdx.x;     // float4 index, 4096 per image
  const float4* xb = (const float4*)(x + (((size_t)b * C_) << 14)) + p4;
  float4 s; s.x = s.y = s.z = s.w = 0.f;
  float4 m; m.x = m.y = m.z = m.w = -INFINITY;
#pragma unroll 4
  for (int c = 0; c < C_; ++c) {
    float4 v = xb[(size_t)c << 12];
    s.x += v.x; s.y += v.y; s.z += v.z; s.w += v.w;
    m.x = fmaxf(m.x, v.x); m.y = fmaxf(m.y, v.y);
    m.z = fmaxf(m.z, v.z); m.w = fmaxf(m.w, v.w);
  }
  float4 sm;
  sm.x = s.x * (1.f / 192.f); sm.y = s.y * (1.f / 192.f);
  sm.z = s.z * (1.f / 192.f); sm.w = s.w * (1.f / 192.f);
  *(float4*)(sp + (size_t)b * 32768 + p4 * 4) = sm;
  *(float4*)(sp + (size_t)b * 32768 + 16384 + p4 * 4) = m;
}

// ---------------- 7x7 conv (2->1 ch) + sigmoid ----------------
__global__ __launch_bounds__(256) void k_spatial_conv(const float* __restrict__ sp, const float* __restrict__ wsp,
                                                      float* __restrict__ sg) {
  int b = blockIdx.y;
  int p = blockIdx.x * 256 + threadIdx.x;
  int y = p >> 7, xx = p & 127;
  const float* s0 = sp + (size_t)b * 32768;
  float acc = 0.f;
  for (int ic = 0; ic < 2; ++ic)
    for (int ky = 0; ky < 7; ++ky) {
      int yy = y + ky - 3;
      if ((unsigned)yy >= 128u) continue;
      for (int kx = 0; kx < 7; ++kx) {
        int xp = xx + kx - 3;
        if ((unsigned)xp >= 128u) continue;
        acc += wsp[ic * 49 + ky * 7 + kx] * s0[ic * 16384 + yy * 128 + xp];
      }
    }
  sg[(size_t)b * 16384 + p] = sigm(acc);
}

// ---------------- gated x, transposed to [hw][c] bf16 ----------------
__global__ __launch_bounds__(256) void k_gxT(const float* __restrict__ x, const float* __restrict__ cg,
                                             const float* __restrict__ sg, u16* __restrict__ gxT, int b0) {
  int zb = blockIdx.y, b = b0 + zb, t = threadIdx.x;
  int hw0 = blockIdx.x * 64;
  __shared__ alignas(16) u16 Ls[64][196];   // row stride 392 B (8-aligned)
  int pq = t & 15, cu = t >> 4;
  int px0 = pq * 4;
  float4 sg4 = *(const float4*)(sg + (size_t)b * 16384 + hw0 + px0);
  float sgp[4] = {sg4.x, sg4.y, sg4.z, sg4.w};
#pragma unroll
  for (int it = 0; it < 3; ++it) {
    int c0 = (it * 16 + cu) * 4;
    float cg0 = cg[b * C_ + c0],     cg1 = cg[b * C_ + c0 + 1];
    float cg2 = cg[b * C_ + c0 + 2], cg3 = cg[b * C_ + c0 + 3];
    float4 v0 = *(const float4*)(x + (((size_t)b * C_ + c0    ) << 14) + hw0 + px0);
    float4 v1 = *(const float4*)(x + (((size_t)b * C_ + c0 + 1) << 14) + hw0 + px0);
    float4 v2 = *(const float4*)(x + (((size_t)b * C_ + c0 + 2) << 14) + hw0 + px0);
    float4 v3 = *(const float4*)(x + (((size_t)b * C_ + c0 + 3) << 14) + hw0 + px0);
    float p0[4] = {v0.x, v0.y, v0.z, v0.w};
    float p1[4] = {v1.x, v1.y, v1.z, v1.w};
    float p2[4] = {v2.x, v2.y, v2.z, v2.w};
    float p3[4] = {v3.x, v3.y, v3.z, v3.w};
#pragma unroll
    for (int p = 0; p < 4; ++p) {
      uint2 w;
      w.x = pk2(f2b(p0[p] * cg0 * sgp[p]), f2b(p1[p] * cg1 * sgp[p]));
      w.y = pk2(f2b(p2[p] * cg2 * sgp[p]), f2b(p3[p] * cg3 * sgp[p]));
      *(uint2*)&Ls[px0 + p][c0] = w;
    }
  }
  __syncthreads();
  uint4* out4 = (uint4*)gxT;                // 24 uint4 per output row (192 u16)
#pragma unroll
  for (int r = 0; r < 6; ++r) {
    int ci = r * 256 + t;                   // 64 rows * 24 uint4
    int row = ci / 24, col4 = ci - row * 24;
    uint2 a = *(const uint2*)&Ls[row][col4 * 8];
    uint2 bq = *(const uint2*)&Ls[row][col4 * 8 + 4];
    uint4 v; v.x = a.x; v.y = a.y; v.z = bq.x; v.w = bq.y;
    out4[((size_t)zb * HW_ + hw0 + row) * 24 + col4] = v;
  }
}

// ---------------- bf16 MFMA GEMM: C[b][M][16384] = A[M][192] * BT[b][16384][192]^T ----------------
// BK=96 (2 k-iterations, 4 barriers) + per-wave LDS repack epilogue for wide stores.
template <int M, typename OutT>
__global__ __launch_bounds__(256) void gemm_bt(const u16* __restrict__ A, const u16* __restrict__ BT,
                                               OutT* __restrict__ C) {
  const int K = 192;
  int b = blockIdx.z;
  int n0 = blockIdx.x * 128, m0 = blockIdx.y * 128;
  const u16* Bb = BT + (size_t)b * HW_ * K;
  __shared__ alignas(16) u16 SMEM[2 * 128 * 104];    // 53248 B
  u16 (*As)[104] = (u16(*)[104])SMEM;
  u16 (*Bs)[104] = (u16(*)[104])(SMEM + 128 * 104);
  int t = threadIdx.x;
  int wave = t >> 6, lane = t & 63, l16 = lane & 15, quad = lane >> 4;
  int wr = wave >> 1, wc = wave & 1;
  v4f acc[4][4] = {};
  for (int kc = 0; kc < K; kc += 96) {
#pragma unroll
    for (int r = 0; r < 6; ++r) {
      int ci = r * 256 + t;          // 1536 chunks of 8 bf16 per operand
      int row = ci / 12, ks = (ci - row * 12) * 8;
      uint4 av; av.x = av.y = av.z = av.w = 0u;
      if (M >= 768 || m0 + row < M) av = *(const uint4*)(A + (size_t)(m0 + row) * K + kc + ks);
      *(uint4*)&As[row][ks] = av;
      uint4 bv = *(const uint4*)(Bb + (size_t)(n0 + row) * K + kc + ks);
      *(uint4*)&Bs[row][ks] = bv;
    }
    __syncthreads();
#pragma unroll
    for (int s = 0; s < 3; ++s) {
      v8s af[4], bf[4];
#pragma unroll
      for (int mt = 0; mt < 4; ++mt) af[mt] = *(const v8s*)&As[wr * 64 + mt * 16 + l16][s * 32 + quad * 8];
#pragma unroll
      for (int nt = 0; nt < 4; ++nt) bf[nt] = *(const v8s*)&Bs[wc * 64 + nt * 16 + l16][s * 32 + quad * 8];
#pragma unroll
      for (int mt = 0; mt < 4; ++mt)
#pragma unroll
        for (int nt = 0; nt < 4; ++nt)
          acc[mt][nt] = __builtin_amdgcn_mfma_f32_16x16x32_bf16(af[mt], bf[nt], acc[mt][nt], 0, 0, 0);
    }
    __syncthreads();
  }
  // epilogue: per-wave private LDS region (10240 B), repack to 16B stores
  char* eb = (char*)SMEM + wave * 10240;
  if constexpr (std::is_same<OutT, u16>::value) {
#pragma unroll
    for (int mt = 0; mt < 4; ++mt)
#pragma unroll
      for (int nt = 0; nt < 4; ++nt)
#pragma unroll
        for (int r = 0; r < 4; ++r) {
          int rr = mt * 16 + quad * 4 + r;
          *(u16*)(eb + rr * 160 + (nt * 16 + l16) * 2) = f2b(acc[mt][nt][r]);
        }
#pragma unroll
    for (int it = 0; it < 8; ++it) {
      int rr = it * 8 + (lane >> 3);
      uint4 v = *(const uint4*)(eb + rr * 160 + (lane & 7) * 16);
      int gm = m0 + wr * 64 + rr;      // M=768: always in-bounds
      size_t off = ((size_t)b * M + gm) * (size_t)HW_ + n0 + wc * 64 + (lane & 7) * 8;
      *(uint4*)(C + off) = v;
    }
  } else {
#pragma unroll
    for (int half = 0; half < 2; ++half) {
#pragma unroll
      for (int mt = 0; mt < 2; ++mt)
#pragma unroll
        for (int nt = 0; nt < 4; ++nt)
#pragma unroll
          for (int r = 0; r < 4; ++r) {
            int rr = mt * 16 + quad * 4 + r;
            *(float*)(eb + rr * 272 + (nt * 16 + l16) * 4) = acc[half * 2 + mt][nt][r];
          }
#pragma unroll
      for (int it = 0; it < 8; ++it) {
        int rr = it * 4 + (lane >> 4);
        uint4 v = *(const uint4*)(eb + rr * 272 + (lane & 15) * 16);
        int gm = m0 + wr * 64 + half * 32 + rr;
        if (gm < M) {
          size_t off = ((size_t)b * M + gm) * (size_t)HW_ + n0 + wc * 64 + (lane & 15) * 4;
          *(uint4*)((float*)C + off) = v;
        }
      }
    }
  }
}

// ---------------- depthwise 3x3 IN-PLACE (bf16, fp32 acc), whole channel in LDS ----------------
// One block per (batch, channel); the full input channel is staged to LDS before any
// write-back, so in-place operation is block-local-safe. Fused q/k inverse-L2-norm.
__global__ __launch_bounds__(256) void k_dw(u16* buf, const float* __restrict__ wdw,
                                            float* __restrict__ rqn, float* __restrict__ rkn, int b0) {
  int oc = blockIdx.x, zb = blockIdx.y;
  size_t base = ((size_t)(zb * C4_ + oc)) << 14;
  int t = threadIdx.x;
  __shared__ alignas(16) u16 Ls[128][128];
  __shared__ float red[256];
  const uint4* gin = (const uint4*)(buf + base);
#pragma unroll
  for (int r = 0; r < 8; ++r) {
    int ci = r * 256 + t;            // 2048 uint4 chunks; 16 chunks per 128-px row
    *(uint4*)&Ls[ci >> 4][(ci & 15) << 3] = gin[ci];
  }
  __syncthreads();
  const float* wd = wdw + oc * 9;
  float w0 = wd[0], w1 = wd[1], w2 = wd[2];
  float w3 = wd[3], w4 = wd[4], w5 = wd[5];
  float w6 = wd[6], w7 = wd[7], w8 = wd[8];
  int x0 = (t & 15) << 3;            // 8-px column segment
  int ybase = (t >> 4) << 3;         // 8 output rows per thread

  float rw[3][10];
  auto ldrow = [&](int yy, float* d) {
    if ((unsigned)yy < 128u) {
      uint4 v = *(const uint4*)&Ls[yy][x0];
      b2f2(v.x, d[1], d[2]); b2f2(v.y, d[3], d[4]);
      b2f2(v.z, d[5], d[6]); b2f2(v.w, d[7], d[8]);
      d[0] = (x0 == 0) ? 0.f : b2f(Ls[yy][x0 - 1]);
      d[9] = (x0 == 120) ? 0.f : b2f(Ls[yy][x0 + 8]);
    } else {
#pragma unroll
      for (int j = 0; j < 10; ++j) d[j] = 0.f;
    }
  };
  ldrow(ybase - 1, rw[0]);
  ldrow(ybase,     rw[1]);
  bool isq = (oc < 192), isk = (oc >= 384 && oc < 576);
  float ssq = 0.f;
#pragma unroll
  for (int oy = 0; oy < 8; ++oy) {
    ldrow(ybase + oy + 1, rw[(oy + 2) % 3]);
    const float* ra = rw[oy % 3];
    const float* rb = rw[(oy + 1) % 3];
    const float* rc = rw[(oy + 2) % 3];
    float acc[8];
#pragma unroll
    for (int j = 0; j < 8; ++j) {
      acc[j] = w0 * ra[j] + w1 * ra[j + 1] + w2 * ra[j + 2]
             + w3 * rb[j] + w4 * rb[j + 1] + w5 * rb[j + 2]
             + w6 * rc[j] + w7 * rc[j + 1] + w8 * rc[j + 2];
    }
    u16 vb[8];
#pragma unroll
    for (int j = 0; j < 8; ++j) vb[j] = f2b(acc[j]);
    uint4 o;
    o.x = pk2(vb[0], vb[1]); o.y = pk2(vb[2], vb[3]);
    o.z = pk2(vb[4], vb[5]); o.w = pk2(vb[6], vb[7]);
    *(uint4*)(buf + base + (((size_t)(ybase + oy)) << 7) + x0) = o;
    if (isq || isk) {
#pragma unroll
      for (int j = 0; j < 8; ++j) { float f = b2f(vb[j]); ssq += f * f; }
    }
  }
  if (isq || isk) {
    red[t] = ssq;
    __syncthreads();
    for (int o2 = 128; o2 > 0; o2 >>= 1) {
      if (t < o2) red[t] += red[t + o2];
      __syncthreads();
    }
    if (t == 0) {
      float r = 1.f / fmaxf(sqrtf(red[0]), 1e-12f);
      int b = b0 + zb;
      if (isq) rqn[b * C_ + oc] = r; else rkn[b * C_ + (oc - 384)] = r;
    }
  }
}

// ---------------- QK^T raw partial dots via MFMA, 4 waves merged in-block ----------------
// split=32 (4 chunks/block): best round-6 config; Spart = 32 partials.
__global__ __launch_bounds__(256) void k_qk(const u16* __restrict__ qkv, float* __restrict__ Spart, int b0) {
  int split = blockIdx.x;
  int zb = blockIdx.y >> 2, h = blockIdx.y & 3;
  int bh = (b0 + zb) * 4 + h;
  int t = threadIdx.x, w = t >> 6, lane = t & 63, l16 = lane & 15, quad = lane >> 4;
  __shared__ union U {
    struct { alignas(16) u16 Qs[48][136]; alignas(16) u16 Ks[48][136]; } qk;
    float R[4][48][49];                  // [wave][d][c], aliased after K-loop
  } Sh;
  const u16* qb = qkv + (((size_t)zb * C4_ + h * 48) << 14);
  const u16* kb = qkv + (((size_t)zb * C4_ + 384 + h * 48) << 14);
  v4f acc[3][3] = {};
  for (int chunk = 0; chunk < 4; ++chunk) {
    int nb = split * 512 + chunk * 128;
#pragma unroll
    for (int r = 0; r < 3; ++r) {
      int ci = r * 256 + t;         // 768 chunks of 8
      int row = ci >> 4, cs = (ci & 15) * 8;
      *(uint4*)&Sh.qk.Qs[row][cs] = *(const uint4*)(qb + ((size_t)row << 14) + nb + cs);
      *(uint4*)&Sh.qk.Ks[row][cs] = *(const uint4*)(kb + ((size_t)row << 14) + nb + cs);
    }
    __syncthreads();
    v8s qf[3], kf[3];
#pragma unroll
    for (int mt = 0; mt < 3; ++mt) qf[mt] = *(const v8s*)&Sh.qk.Qs[mt * 16 + l16][w * 32 + quad * 8];
#pragma unroll
    for (int nt = 0; nt < 3; ++nt) kf[nt] = *(const v8s*)&Sh.qk.Ks[nt * 16 + l16][w * 32 + quad * 8];
#pragma unroll
    for (int mt = 0; mt < 3; ++mt)
#pragma unroll
      for (int nt = 0; nt < 3; ++nt)
        acc[mt][nt] = __builtin_amdgcn_mfma_f32_16x16x32_bf16(qf[mt], kf[nt], acc[mt][nt], 0, 0, 0);
    __syncthreads();
  }
  // dump wave partials (Qs/Ks dead now) and reduce 4 -> 1 in-block
#pragma unroll
  for (int mt = 0; mt < 3; ++mt)
#pragma unroll
    for (int nt = 0; nt < 3; ++nt)
#pragma unroll
      for (int r = 0; r < 4; ++r)
        Sh.R[w][nt * 16 + l16][mt * 16 + quad * 4 + r] = acc[mt][nt][r];
  __syncthreads();
  float* out = Spart + ((size_t)split * 32 + bh) * 2304;
#pragma unroll
  for (int rr = 0; rr < 9; ++rr) {
    int e = rr * 256 + t;
    int c = e / 48, d = e - c * 48;
    out[e] = (Sh.R[0][d][c] + Sh.R[1][d][c]) + (Sh.R[2][d][c] + Sh.R[3][d][c]);
  }
}

// ---------------- parallel Spart reduction + norm/temperature fold ----------------
__global__ __launch_bounds__(256) void k_sred(const float* __restrict__ Spart, const float* __restrict__ rqn,
                                              const float* __restrict__ rkn, const float* __restrict__ temp,
                                              float* __restrict__ Sm, int b0) {
  int bh = b0 * 4 + blockIdx.y;
  int b = bh >> 2, h = bh & 3, t = threadIdx.x;
  int e = blockIdx.x * 256 + t;
  float s = 0.f;
#pragma unroll
  for (int p = 0; p < 32; ++p) s += Spart[((size_t)p * 32 + bh) * 2304 + e];
  int c = e / 48, d = e - c * 48;
  Sm[(size_t)bh * 2304 + e] = s * rqn[b * C_ + h * 48 + c] * rkn[b * C_ + h * 48 + d] * temp[h];
}

// ---------------- softmax rows (Sm pre-reduced & scaled) ----------------
__global__ __launch_bounds__(256) void k_softmax(const float* __restrict__ Sm_g, float* __restrict__ attn, int b0) {
  int bh = b0 * 4 + blockIdx.x;
  int t = threadIdx.x;
  __shared__ float Sm[2304];
  for (int r = 0; r < 9; ++r) {
    int e = r * 256 + t;
    Sm[e] = Sm_g[(size_t)bh * 2304 + e];
  }
  __syncthreads();
  if (t < 48) {
    float m = -INFINITY;
#pragma unroll
    for (int d = 0; d < 48; ++d) m = fmaxf(m, Sm[t * 48 + d]);
    float ex[48];
    float sum = 0.f;
#pragma unroll
    for (int d = 0; d < 48; ++d) { ex[d] = expf(Sm[t * 48 + d] - m); sum += ex[d]; }
    float inv = 1.f / sum;
#pragma unroll
    for (int d = 0; d < 48; ++d) attn[(size_t)bh * 2304 + t * 48 + d] = ex[d] * inv;
  }
}

// ---------------- out = (attn @ v) * sigmoid(gate), stored as ogT[hw][c] bf16 ----------------
// 256-px n-tiles: LDS 34.6KB -> 4 blocks/CU.
__global__ __launch_bounds__(256) void k_av(const u16* __restrict__ qkv, const float* __restrict__ attn,
                                            u16* __restrict__ ogT, int b0) {
  int zb = blockIdx.y >> 2, h = blockIdx.y & 3;
  int bh = (b0 + zb) * 4 + h;
  int t = threadIdx.x;
  int n0 = blockIdx.x * 256;
  __shared__ alignas(16) u16 Vs[48][264];
  __shared__ alignas(16) float SlT[48][48];   // [d][c]
  for (int r = 0; r < 9; ++r) {
    int e = r * 256 + t;
    int c = e / 48, d = e - c * 48;
    SlT[d][c] = attn[(size_t)bh * 2304 + e];
  }
  const u16* vb = qkv + (((size_t)zb * C4_ + 576 + h * 48) << 14);
#pragma unroll
  for (int r = 0; r < 6; ++r) {
    int ci = r * 256 + t;           // 48 rows * 32 chunks
    int row = ci >> 5, cs = (ci & 31) * 8;
    *(uint4*)&Vs[row][cs] = *(const uint4*)(vb + ((size_t)row << 14) + n0 + cs);
  }
  __syncthreads();
  int grp = t >> 6, nl = t & 63;
  int n = n0 + nl * 4;
  float acc[12][4] = {};
  for (int d = 0; d < 48; ++d) {
    uint2 vv = *(const uint2*)&Vs[d][nl * 4];
    float v[4];
    b2f2(vv.x, v[0], v[1]); b2f2(vv.y, v[2], v[3]);
    const float4* sr = (const float4*)&SlT[d][grp * 12];
    float4 sa = sr[0], sb = sr[1], sc = sr[2];
    float sv[12] = {sa.x, sa.y, sa.z, sa.w, sb.x, sb.y, sb.z, sb.w, sc.x, sc.y, sc.z, sc.w};
#pragma unroll
    for (int cc = 0; cc < 12; ++cc)
#pragma unroll
      for (int j = 0; j < 4; ++j) acc[cc][j] += sv[cc] * v[j];
  }
  const u16* gb = qkv + (((size_t)zb * C4_ + 192 + h * 48) << 14);
#pragma unroll
  for (int cc = 0; cc < 12; ++cc) {
    int c = grp * 12 + cc;
    uint2 g4 = *(const uint2*)(gb + ((size_t)c << 14) + n);
    float g[4];
    b2f2(g4.x, g[0], g[1]); b2f2(g4.y, g[2], g[3]);
#pragma unroll
    for (int j = 0; j < 4; ++j) acc[cc][j] *= sigm(g[j]);
  }
#pragma unroll
  for (int j = 0; j < 4; ++j) {
    u16 vals[12];
#pragma unroll
    for (int cc = 0; cc < 12; ++cc) vals[cc] = f2b(acc[cc][j]);
    u16* dst = ogT + ((size_t)zb * HW_ + n + j) * 192 + h * 48 + grp * 12;
    uint2* d2 = (uint2*)dst;        // 8-byte aligned
    uint2 w0, w1, w2;
    w0.x = pk2(vals[0], vals[1]);  w0.y = pk2(vals[2], vals[3]);
    w1.x = pk2(vals[4], vals[5]);  w1.y = pk2(vals[6], vals[7]);
    w2.x = pk2(vals[8], vals[9]);  w2.y = pk2(vals[10], vals[11]);
    d2[0] = w0; d2[1] = w1; d2[2] = w2;
  }
}

// ---------------- host ----------------
extern "C" void kernel_launch(void* const* d_in, const int* in_sizes, int n_in,
                              void* d_out, int out_size, void* d_ws, size_t ws_size,
                              hipStream_t stream) {
  const float* x     = (const float*)d_in[0];
  const float* wfc1  = (const float*)d_in[1];
  const float* wfc2  = (const float*)d_in[2];
  const float* wsp   = (const float*)d_in[3];
  const float* wqkv  = (const float*)d_in[4];
  const float* wdw   = (const float*)d_in[5];
  const float* wproj = (const float*)d_in[6];
  const float* temp  = (const float*)d_in[7];
  float* out = (float*)d_out;
  char* W = (char*)d_ws;

  constexpr size_t OFF_AVG   = 0;
  constexpr size_t OFF_MAX   = 8192;
  constexpr size_t OFF_CG    = 16384;
  constexpr size_t OFF_RQN   = 24576;
  constexpr size_t OFF_RKN   = 32768;
  constexpr size_t OFF_WQB   = 40960;
  constexpr size_t OFF_WPB   = OFF_WQB + 294912;
  constexpr size_t OFF_SP    = OFF_WPB + 73728;
  constexpr size_t OFF_SG    = OFF_SP + 1048576;
  constexpr size_t OFF_ATT   = OFF_SG + 524288;
  constexpr size_t OFF_SM    = OFF_ATT + 294912;      // scaled S: 32 bh x 2304 x 4B
  constexpr size_t OFF_SPART = OFF_SM + 294912;
  constexpr size_t OFF_BIG   = OFF_SPART + 9437184;   // Spart: 32 partials x 32 bh x 2304 x 4B
  const size_t GXT_B = (size_t)HW_ * 192 * 2;        // 6291456 (also holds ogT later)
  const size_t QKV_B = (size_t)C4_ * HW_ * 2;        // 25165824 (in-place dw)

  float* avg   = (float*)(W + OFF_AVG);
  float* mx    = (float*)(W + OFF_MAX);
  float* cg    = (float*)(W + OFF_CG);
  float* rqn   = (float*)(W + OFF_RQN);
  float* rkn   = (float*)(W + OFF_RKN);
  u16*   wqb   = (u16*)(W + OFF_WQB);
  u16*   wpb   = (u16*)(W + OFF_WPB);
  float* sp    = (float*)(W + OFF_SP);
  float* sg    = (float*)(W + OFF_SG);
  float* attn  = (float*)(W + OFF_ATT);
  float* Smg   = (float*)(W + OFF_SM);
  float* Spart = (float*)(W + OFF_SPART);

  int NB = 8;
  while (NB > 1 && (OFF_BIG + (size_t)NB * (GXT_B + QKV_B)) > ws_size) NB >>= 1;

  u16* gxT  = (u16*)(W + OFF_BIG);
  u16* qkv  = (u16*)(W + OFF_BIG + (size_t)NB * GXT_B);   // raw, then dw'd in place
  u16* ogT  = gxT;   // gxT dead once gemm768 has consumed it

  k_f2bw<<<(184320 + 255) / 256, 256, 0, stream>>>(wqkv, wproj, wqb, wpb);
  k_channel_pool<<<dim3(C_, B_), 256, 0, stream>>>(x, avg, mx);
  k_channel_gate<<<B_, 256, 0, stream>>>(avg, mx, wfc1, wfc2, cg);
  k_spatial_pool<<<dim3(16, B_), 256, 0, stream>>>(x, sp);
  k_spatial_conv<<<dim3(64, B_), 256, 0, stream>>>(sp, wsp, sg);

  for (int b0 = 0; b0 < B_; b0 += NB) {
    k_gxT<<<dim3(256, NB), 256, 0, stream>>>(x, cg, sg, gxT, b0);
    gemm_bt<768, u16><<<dim3(128, 6, NB), 256, 0, stream>>>(wqb, gxT, qkv);
    k_dw<<<dim3(C4_, NB), 256, 0, stream>>>(qkv, wdw, rqn, rkn, b0);
    k_qk<<<dim3(32, NB * 4), 256, 0, stream>>>(qkv, Spart, b0);
    k_sred<<<dim3(9, NB * 4), 256, 0, stream>>>(Spart, rqn, rkn, temp, Smg, b0);
    k_softmax<<<NB * 4, 256, 0, stream>>>(Smg, attn, b0);
    k_av<<<dim3(64, NB * 4), 256, 0, stream>>>(qkv, attn, ogT, b0);
    gemm_bt<192, float><<<dim3(128, 2, NB), 256, 0, stream>>>(wpb, ogT, out + (size_t)b0 * C_ * HW_);
  }
}